// Round 11
// baseline (111.780 us; speedup 1.0000x reference)
//
#include <hip/hip_runtime.h>
#include <stdint.h>

// DiscreteMarkovDynamics: 5-step Markov jump sim, B=32, L=4096, V=512.
// R1: table precompute + wave-per-position categorical -> 1024 us.
// R2: provable-reject skip (u >= pthr[s] => categorical dead code) -> 250 us.
// R3-R8: parallel build; ballot candidate scan; scheduling experiments ->
//     best = R8: 2048x256 residency, LDS chunk-pull, markov 44 us.
// R9: screen/jump kernel split = wash; proved cheap-screen + P-table (absmax 0).
//     Exposed ~65-70 us harness floor (268 MB ws re-poison + restore train).
// R10: R8 scheduling + R9 cuts -> markov 43: instruction cuts didn't move it,
//     so the binding constant is the per-candidate SERIAL critical path
//     (threefry + TWO 6-level shfl butterflies + dependent loads).
// R11: certified one-butterfly argmax: carry top-2 (b1,i1,b2) through ONE
//     cheap butterfly; if b1-b2 > 2*EPS the exact argmax provably equals i1
//     (no exact logf, no 2nd butterfly). Ties/close calls (~2-3%) fall back
//     to R10's byte-identical exact path.

#define VOCAB  512
#define EMB    256
#define HID    64
#define NPOS   (32 * 4096)   // B*L = 131072
#define STEPS  5
#define PPW    8             // positions per chunk; PPW*STEPS=40 <= 64 lanes
#define CHUNKS (NPOS / PPW)  // 16384
#define MBLK   2048          // markov blocks; 8 chunks per block
#define CPB    (CHUNKS / MBLK)  // 8

// Exact mirror of jax._src.prng.threefry2x32 (20 rounds).
__host__ __device__ __forceinline__ void tf2x32(uint32_t k0, uint32_t k1,
                                                uint32_t x0, uint32_t x1,
                                                uint32_t& o0, uint32_t& o1) {
  uint32_t ks2 = k0 ^ k1 ^ 0x1BD11BDAu;
  x0 += k0; x1 += k1;
#define TFR(r) { x0 += x1; x1 = (x1 << (r)) | (x1 >> (32 - (r))); x1 ^= x0; }
  TFR(13) TFR(15) TFR(26) TFR(6)
  x0 += k1;  x1 += ks2 + 1u;
  TFR(17) TFR(29) TFR(16) TFR(24)
  x0 += ks2; x1 += k0 + 2u;
  TFR(13) TFR(15) TFR(26) TFR(6)
  x0 += k0;  x1 += k1 + 3u;
  TFR(17) TFR(29) TFR(16) TFR(24)
  x0 += k1;  x1 += ks2 + 4u;
  TFR(13) TFR(15) TFR(26) TFR(6)
  x0 += ks2; x1 += k0 + 5u;
#undef TFR
  o0 = x0; o1 = x1;
}

struct Keys {
  uint32_t k1a[STEPS], k1b[STEPS];  // categorical (gumbel) keys per step
  uint32_t k2a[STEPS], k2b[STEPS];  // accept-uniform keys per step
};

// Fused table build (R9/R10-proven math, bit-identical).
__global__ __launch_bounds__(512)
void build_table(const float* __restrict__ emb,
                 const float* __restrict__ W1,
                 const float* __restrict__ b1,
                 const float* __restrict__ W2,
                 const float* __restrict__ b2,
                 float* __restrict__ I,
                 float* __restrict__ P,
                 float* __restrict__ pthr) {
  const int s   = blockIdx.x;
  const int tid = threadIdx.x;
  __shared__ double part[8][HID];
  __shared__ double hd[HID];
  __shared__ float  redmax[8];

  const int hid = tid & (HID - 1);
  const int kq  = tid >> 6;               // 0..7, k = kq + 8*i
  const float* e = emb + s * EMB;
  double acc = 0.0;
#pragma unroll
  for (int ib = 0; ib < 32; ib += 16) {   // two 16-wide load batches
    float ev[16], wv[16];
#pragma unroll
    for (int i = 0; i < 16; ++i) {
      const int k = kq + 8 * (ib + i);
      ev[i] = e[k];
      wv[i] = W1[k * HID + hid];
    }
#pragma unroll
    for (int i = 0; i < 16; ++i)          // same fp64 order as R4-R10
      acc += (double)ev[i] * (double)wv[i];
  }
  part[kq][hid] = acc;
  __syncthreads();
  if (kq == 0) {
    const double a = ((part[0][hid] + part[1][hid]) + (part[2][hid] + part[3][hid]))
                   + ((part[4][hid] + part[5][hid]) + (part[6][hid] + part[7][hid]));
    const float m = (float)a + b1[hid];
    hd[hid] = (double)(m > 0.0f ? m : 0.0f);   // relu
  }
  __syncthreads();

  double acc2 = 0.0;
#pragma unroll
  for (int kb = 0; kb < HID; kb += 16) {
    float wv[16];
#pragma unroll
    for (int i = 0; i < 16; ++i)
      wv[i] = W2[(kb + i) * VOCAB + tid];
#pragma unroll
    for (int i = 0; i < 16; ++i)
      acc2 += hd[kb + i] * (double)wv[i];
  }
  const float val = (float)acc2 + b2[tid];
  I[s * VOCAB + tid] = val;
  const float z = (-val) * 0.01f;               // accept-path op chain
  const float pv = 1.0f - (float)exp((double)z);
  P[s * VOCAB + tid] = pv;

  float lmax = pv;                         // max over P (order-insensitive)
  for (int off = 32; off > 0; off >>= 1)
    lmax = fmaxf(lmax, __shfl_xor(lmax, off, 64));
  if ((tid & 63) == 0) redmax[tid >> 6] = lmax;
  __syncthreads();
  if (tid == 0) {
    float m = redmax[0];
#pragma unroll
    for (int i = 1; i < 8; ++i) m = fmaxf(m, redmax[i]);
    pthr[s] = m;
  }
}

// Markov kernel: R8 scheduling + R11 one-butterfly certified categorical.
__global__ __launch_bounds__(256)
void markov_kernel(const int* __restrict__ x_in,
                   const float* __restrict__ I,
                   const float* __restrict__ P,
                   const float* __restrict__ pthr,
                   int* __restrict__ x_out,
                   Keys K) {
  __shared__ int next_chunk;
  if (threadIdx.x == 0) next_chunk = 0;
  __syncthreads();

  const int lane = threadIdx.x & 63;
  const int qp = lane / 5;                 // lane q -> (position, step)
  const int qt = lane - qp * 5;
  const float TINYF = 1.17549435e-38f;
  const float NEGINF = -__builtin_inff();
  const float MARGIN = 0.015625f;          // 2*EPS; cheap-log err <= ~5e-6

  for (;;) {
    int c = 0;
    if (lane == 0) c = atomicAdd(&next_chunk, 1);   // LDS atomic: cheap
    c = __shfl(c, 0, 64);                            // wave-uniform
    if (c >= CPB) break;
    const int base = (blockIdx.x * CPB + c) * PPW;

    // States (lanes 0..7), then per-position pthr, shfl'd to the test lanes.
    int scur = (lane < PPW) ? x_in[base + lane] : 0;
    const float pv = (lane < PPW) ? pthr[scur] : 0.0f;

    // Accept uniforms: lane q < 40 holds u for (p=q/5, t=q%5).
    float u40 = 0.0f;
    if (lane < PPW * STEPS) {
      uint32_t w0, w1;
      tf2x32(K.k2a[qt], K.k2b[qt], 0u, (uint32_t)(base + qp), w0, w1);
      u40 = __uint_as_float((((w0 ^ w1) >> 9) | 0x3f800000u)) - 1.0f;
    }

    // Candidate mask: u_q < pthr[s_p] (state fixed unless an accept occurs).
    const float pq = __shfl(pv, qp, 64);
    const bool cand = (lane < PPW * STEPS) && (u40 < pq);
    unsigned long long mask = __ballot(cand);

    while (mask) {
      const int q = (int)__builtin_ctzll(mask);   // wave-uniform
      mask &= mask - 1;
      const int p = q / 5;
      const int t = q - p * 5;
      const int s = __builtin_amdgcn_readfirstlane(__shfl(scur, p, 64));

      // ---- Categorical: cheap top-2, certified one-butterfly argmax ----
      const float* row = I + s * VOCAB;
      float rv[8];
#pragma unroll
      for (int j = 0; j < 8; ++j)               // prefetch row values (L2)
        rv[j] = row[lane + (j << 6)];

      const uint32_t fbase = ((uint32_t)(base + p) << 9) + (uint32_t)lane;
      uint32_t bits[8];
#pragma unroll
      for (int j = 0; j < 8; ++j) {             // 8 independent threefry
        uint32_t w0, w1;
        tf2x32(K.k1a[t], K.k1b[t], 0u, fbase + ((uint32_t)j << 6), w0, w1);
        bits[j] = w0 ^ w1;
      }

      // Cheap pass: hardware-log gumbel approx, lane-local top-2.
      float valC[8];
      float b1 = NEGINF, b2 = NEGINF;
      int   i1 = 0x7FFFFFFF;
#pragma unroll
      for (int j = 0; j < 8; ++j) {
        float ufv = __uint_as_float((bits[j] >> 9) | 0x3f800000u) - 1.0f;
        if (ufv == 0.0f) ufv = TINYF;
        const float gC = -__logf(-__logf(ufv));
        const int v = lane + (j << 6);
        const float vc = (v == s) ? NEGINF : rv[j] + gC;
        valC[j] = vc;
        if (vc > b1)      { b2 = b1; b1 = vc; i1 = v; }
        else if (vc > b2) { b2 = vc; }
      }
      // ONE butterfly carrying (b1, i1, b2). Merged second-best law:
      // b2' = max(min(b1,ob1), b2, ob2) -> equal top-1s force gap 0.
      for (int off = 32; off > 0; off >>= 1) {
        const float ob1 = __shfl_xor(b1, off, 64);
        const int   oi1 = __shfl_xor(i1, off, 64);
        const float ob2 = __shfl_xor(b2, off, 64);
        const float losr = fminf(b1, ob1);
        b2 = fmaxf(losr, fmaxf(b2, ob2));
        if (ob1 > b1 || (ob1 == b1 && oi1 < i1)) { b1 = ob1; i1 = oi1; }
      }

      int bidx;
      if (b1 - b2 > MARGIN) {
        // Certified: exact argmax provably == cheap argmax (unique).
        bidx = i1;
      } else {
        // Exact fallback (~2-3%): byte-identical to the reference ops on the
        // shortlist; excluded j are provably below the exact max.
        const float thresh = b1 - MARGIN;
        float best = NEGINF;
        int bx = 0x7FFFFFFF;
#pragma unroll
        for (int j = 0; j < 8; ++j) {
          if (valC[j] >= thresh) {
            float ufv = __uint_as_float((bits[j] >> 9) | 0x3f800000u) - 1.0f;
            if (ufv == 0.0f) ufv = TINYF;
            const float g = -logf(-logf(ufv));
            const float val = rv[j] + g;
            const int v = lane + (j << 6);
            if (val > best) { best = val; bx = v; }  // j asc -> first index
          }
        }
        for (int off = 32; off > 0; off >>= 1) {
          const float ob = __shfl_xor(best, off, 64);
          const int   oi = __shfl_xor(bx, off, 64);
          if (ob > best || (ob == best && oi < bx)) { best = ob; bx = oi; }
        }
        bidx = bx;
      }
      bidx = __builtin_amdgcn_readfirstlane(bidx);

      const float pacc = P[s * VOCAB + bidx];   // P-table accept (bit-exact)
      const float u = __shfl(u40, q, 64);
      if (u < pacc) {
        if (lane == p) scur = bidx;                     // accept jump
        // Re-evaluate this position's FUTURE steps under the new state.
        const unsigned long long fut =
            (((1ull << (p * 5 + 5)) - 1) & ~((1ull << (q + 1)) - 1));
        const float pnew = pthr[bidx];                  // scalar (bidx uniform)
        const unsigned long long nb = __ballot(u40 < pnew) & fut;
        mask = (mask & ~fut) | nb;
      }
    }
    if (lane < PPW) x_out[base + lane] = scur;
  }
}

extern "C" void kernel_launch(void* const* d_in, const int* in_sizes, int n_in,
                              void* d_out, int out_size, void* d_ws, size_t ws_size,
                              hipStream_t stream) {
  const int*   x   = (const int*)d_in[0];
  const float* emb = (const float*)d_in[1];
  const float* W1  = (const float*)d_in[2];
  const float* b1  = (const float*)d_in[3];
  const float* W2  = (const float*)d_in[4];
  const float* b2  = (const float*)d_in[5];
  float* I    = (float*)d_ws;                        // 1 MiB
  float* P    = I + VOCAB * VOCAB;                   // 1 MiB
  float* pthr = P + VOCAB * VOCAB;                   // 2 KiB
  int* out = (int*)d_out;

  // Host-side key derivation (partitionable scheme):
  //   key(42) = (0,42); split -> S_t = tf(key,(0,t)); (k1,k2) = tf(S_t,(0,j))
  Keys K;
  for (int t = 0; t < STEPS; ++t) {
    uint32_t Sa, Sb;
    tf2x32(0u, 42u, 0u, (uint32_t)t, Sa, Sb);
    tf2x32(Sa, Sb, 0u, 0u, K.k1a[t], K.k1b[t]);
    tf2x32(Sa, Sb, 0u, 1u, K.k2a[t], K.k2b[t]);
  }

  build_table<<<VOCAB, 512, 0, stream>>>(emb, W1, b1, W2, b2, I, P, pthr);
  markov_kernel<<<MBLK, 256, 0, stream>>>(x, I, P, pthr, out, K);
}